// Round 12
// baseline (896.458 us; speedup 1.0000x reference)
//
#include <hip/hip_runtime.h>
#include <math.h>

__device__ __forceinline__ float leaky02(float v) { return v > 0.f ? v : 0.2f * v; }
__device__ __forceinline__ float eluf(float v) { return v > 0.f ? v : __expf(v) - 1.f; }
__device__ __forceinline__ float expc(float v) { return __expf(fminf(v, 60.f)); }
// bf16 pack/unpack (RNE)
__device__ __forceinline__ unsigned short f2bf(float f) {
    unsigned int u = __float_as_uint(f);
    return (unsigned short)((u + 0x7FFFu + ((u >> 16) & 1u)) >> 16);
}
__device__ __forceinline__ float bflo(unsigned int u) { return __uint_as_float(u << 16); }
__device__ __forceinline__ float bfhi(unsigned int u) { return __uint_as_float(u & 0xFFFF0000u); }

// ---------------- init counts to 1 (self-loop per node) ----------------
__global__ __launch_bounds__(256) void k_init1(int* __restrict__ p, int n) {
    int t = blockIdx.x * 256 + threadIdx.x;
    if (t < n) p[t] = 1;
}

// ---------------- GEMM1: h1(bf16) = x @ w1 (+ as1/ad1) ----------------
__global__ __launch_bounds__(256, 2) void k_gemm1(
    const float* __restrict__ x, const float* __restrict__ w1,
    const float* __restrict__ a1s, const float* __restrict__ a1d,
    unsigned short* __restrict__ h1b, float* __restrict__ as1, float* __restrict__ ad1, int N)
{
    __shared__ float xs[64 * 128];   // 32 KB, swizzled
    __shared__ float wsh[128 * 64];  // 32 KB
    const int half = blockIdx.x & 1;
    const int tile = blockIdx.x >> 1;
    const int tid  = threadIdx.x;
    const int r_base = tile * 64;

    for (int i = tid; i < 2048; i += 256) {
        int k = i >> 4, c4 = i & 15;
        float4 v = *(const float4*)(w1 + k * 128 + half * 64 + c4 * 4);
        *(float4*)(wsh + k * 64 + c4 * 4) = v;
    }
    for (int i = tid; i < 2048; i += 256) {
        int r = i >> 5, k4 = i & 31;
        int rr = r_base + r; if (rr >= N) rr = N - 1;
        float4 v = *(const float4*)(x + (size_t)rr * 128 + k4 * 4);
        *(float4*)(xs + r * 128 + (k4 ^ (r & 7)) * 4) = v;
    }
    __syncthreads();

    const int c0 = (tid & 15) * 4;
    const int r0 = (tid >> 4) * 4;
    const int swz0 = ((r0 + 0) & 7) << 2;
    const int swz1 = ((r0 + 1) & 7) << 2;
    const int swz2 = ((r0 + 2) & 7) << 2;
    const int swz3 = ((r0 + 3) & 7) << 2;
    const float* xb0 = xs + (r0 + 0) * 128;
    const float* xb1 = xs + (r0 + 1) * 128;
    const float* xb2 = xs + (r0 + 2) * 128;
    const float* xb3 = xs + (r0 + 3) * 128;

    float4 acc0 = {0,0,0,0}, acc1 = {0,0,0,0}, acc2 = {0,0,0,0}, acc3 = {0,0,0,0};
#pragma unroll 4
    for (int k = 0; k < 128; ++k) {
        float4 wv = *(const float4*)(wsh + k * 64 + c0);
        float x0 = xb0[k ^ swz0];
        float x1 = xb1[k ^ swz1];
        float x2 = xb2[k ^ swz2];
        float x3 = xb3[k ^ swz3];
        acc0.x = fmaf(x0, wv.x, acc0.x); acc0.y = fmaf(x0, wv.y, acc0.y);
        acc0.z = fmaf(x0, wv.z, acc0.z); acc0.w = fmaf(x0, wv.w, acc0.w);
        acc1.x = fmaf(x1, wv.x, acc1.x); acc1.y = fmaf(x1, wv.y, acc1.y);
        acc1.z = fmaf(x1, wv.z, acc1.z); acc1.w = fmaf(x1, wv.w, acc1.w);
        acc2.x = fmaf(x2, wv.x, acc2.x); acc2.y = fmaf(x2, wv.y, acc2.y);
        acc2.z = fmaf(x2, wv.z, acc2.z); acc2.w = fmaf(x2, wv.w, acc2.w);
        acc3.x = fmaf(x3, wv.x, acc3.x); acc3.y = fmaf(x3, wv.y, acc3.y);
        acc3.z = fmaf(x3, wv.z, acc3.z); acc3.w = fmaf(x3, wv.w, acc3.w);
    }

    const int cg = half * 64 + c0;
    const float4 avs = *(const float4*)(a1s + cg);
    const float4 avd = *(const float4*)(a1d + cg);
    const int head = half * 2 + ((tid & 15) >> 3);
    float4 accs[4] = {acc0, acc1, acc2, acc3};
#pragma unroll
    for (int i = 0; i < 4; ++i) {
        int r = r_base + r0 + i;
        float4 a = accs[i];
        float ps = a.x * avs.x + a.y * avs.y + a.z * avs.z + a.w * avs.w;
        float pd = a.x * avd.x + a.y * avd.y + a.z * avd.z + a.w * avd.w;
        ps += __shfl_xor(ps, 1); pd += __shfl_xor(pd, 1);
        ps += __shfl_xor(ps, 2); pd += __shfl_xor(pd, 2);
        ps += __shfl_xor(ps, 4); pd += __shfl_xor(pd, 4);
        if (r < N) {
            ushort4 hb;
            hb.x = f2bf(a.x); hb.y = f2bf(a.y); hb.z = f2bf(a.z); hb.w = f2bf(a.w);
            *(ushort4*)(h1b + (size_t)r * 128 + cg) = hb;
            if ((tid & 7) == 0) {
                as1[(size_t)r * 4 + head] = ps;
                ad1[(size_t)r * 4 + head] = pd;
            }
        }
    }
}

// ---------------- CSR build ----------------
__global__ __launch_bounds__(256) void k_hist(const int* __restrict__ ei, int* __restrict__ counts,
                                              int E) {
    int t = blockIdx.x * 256 + threadIdx.x;
    if (t >= E) return;
    atomicAdd(&counts[ei[E + t]], 1);
}

__global__ __launch_bounds__(256) void k_bsum(const int* __restrict__ counts,
                                              int* __restrict__ bsum, int N) {
    int t = threadIdx.x;
    int base = blockIdx.x * 1024 + t * 4;
    int s = 0;
    if (base + 3 < N) { int4 v = *(const int4*)(counts + base); s = v.x + v.y + v.z + v.w; }
    else { for (int j = 0; j < 4; ++j) if (base + j < N) s += counts[base + j]; }
#pragma unroll
    for (int off = 1; off < 64; off <<= 1) s += __shfl_xor(s, off);
    __shared__ int wt[4];
    if ((t & 63) == 0) wt[t >> 6] = s;
    __syncthreads();
    if (t == 0) bsum[blockIdx.x] = wt[0] + wt[1] + wt[2] + wt[3];
}

__global__ __launch_bounds__(1024) void k_scansums(const int* __restrict__ bsum,
                                                   int* __restrict__ boff,
                                                   int* __restrict__ rowp_last, int NB) {
    __shared__ int ps[1024];
    int t = threadIdx.x;
    int v = (t < NB) ? bsum[t] : 0;
    ps[t] = v;
    __syncthreads();
    for (int off = 1; off < 1024; off <<= 1) {
        int u = (t >= off) ? ps[t - off] : 0;
        __syncthreads();
        ps[t] += u;
        __syncthreads();
    }
    if (t < NB) boff[t] = ps[t] - v;
    if (t == NB - 1) *rowp_last = ps[t];
}

__global__ __launch_bounds__(256) void k_scatter(const int* __restrict__ counts,
                                                 const int* __restrict__ boff,
                                                 int* __restrict__ rowp, int N) {
    int t = threadIdx.x;
    int lane = t & 63, wv = t >> 6;
    int base = blockIdx.x * 1024 + t * 4;
    int c0 = 0, c1 = 0, c2 = 0, c3 = 0;
    if (base + 3 < N) { int4 v = *(const int4*)(counts + base); c0 = v.x; c1 = v.y; c2 = v.z; c3 = v.w; }
    else {
        if (base     < N) c0 = counts[base];
        if (base + 1 < N) c1 = counts[base + 1];
        if (base + 2 < N) c2 = counts[base + 2];
        if (base + 3 < N) c3 = counts[base + 3];
    }
    int ts = c0 + c1 + c2 + c3;
    int inc = ts;
#pragma unroll
    for (int off = 1; off < 64; off <<= 1) { int u = __shfl_up(inc, off); if (lane >= off) inc += u; }
    int excl = inc - ts;
    __shared__ int wt[4];
    if (lane == 63) wt[wv] = inc;
    __syncthreads();
    int woff = 0;
    for (int i = 0; i < wv; ++i) woff += wt[i];
    int p = boff[blockIdx.x] + woff + excl;
    if (base     < N) { rowp[base]     = p; p += c0; }
    if (base + 1 < N) { rowp[base + 1] = p; p += c1; }
    if (base + 2 < N) { rowp[base + 2] = p; p += c2; }
    if (base + 3 < N) { rowp[base + 3] = p; p += c3; }
}

// bucket cursors: bq[b] = rowp[b*128]  (bucket b = nodes [128b, 128b+128))
__global__ __launch_bounds__(1024) void k_binit(const int* __restrict__ rowp,
                                                int* __restrict__ bq, int NBk) {
    int t = threadIdx.x;
    if (t < NBk) bq[t] = rowp[t * 128];
}

// pass B: append (src,dst) to dst's bucket region (dense tail-line writes)
__global__ __launch_bounds__(256) void k_bucket(
    const int* __restrict__ ei, int* __restrict__ bq,
    int2* __restrict__ ebuf, int E, int Et)
{
    int t = blockIdx.x * 256 + threadIdx.x;
    if (t >= Et) return;
    int s, dd;
    if (t < E) { s = ei[t]; dd = ei[E + t]; } else { s = dd = t - E; }
    int p = atomicAdd(&bq[dd >> 7], 1);
    ebuf[p] = make_int2(s, dd);
}

// pass C: per-bucket local counting sort via LDS cursors; col writes are dense
__global__ __launch_bounds__(256) void k_csort(
    const int* __restrict__ rowp, const int2* __restrict__ ebuf,
    int* __restrict__ col, int N)
{
    __shared__ int cnt[128];
    const int b = blockIdx.x;
    const int nb0 = b * 128;
    const int tid = threadIdx.x;
    int nb1 = nb0 + 128; if (nb1 > N) nb1 = N;
    if (tid < 128) {
        int node = nb0 + tid;
        cnt[tid] = (node < N) ? rowp[node] : 0;
    }
    __syncthreads();
    const int j0 = rowp[nb0];
    const int j1 = rowp[nb1];
    for (int j = j0 + tid; j < j1; j += 256) {
        int2 e = ebuf[j];
        int p = atomicAdd(&cnt[e.y - nb0], 1);
        col[p] = e.x;
    }
}

// ---------------- layer-1 aggregation (wave per dst node) ----------------
__global__ __launch_bounds__(256) void k_agg1(
    const int* __restrict__ rowp, const int* __restrict__ col,
    const float* __restrict__ as1, const float* __restrict__ ad1,
    const unsigned short* __restrict__ h1b,
    const float* __restrict__ b1, float* __restrict__ out1, int N)
{
    const int lane = threadIdx.x & 63;
    const int wid  = (blockIdx.x * 256 + threadIdx.x) >> 6;
    const int nw   = (gridDim.x * 256) >> 6;
    const int q    = lane >> 4;      // 0..3: edge slot
    const int cl8  = lane & 15;      // owns channels cl8*8 .. cl8*8+7
    const int hch  = cl8 >> 2;       // head of this channel group
    for (int n = wid; n < N; n += nw) {
        const int start = rowp[n], end = rowp[n + 1];
        const float4 ad4 = *(const float4*)(ad1 + (size_t)n * 4);
        float4 ds = {0.f, 0.f, 0.f, 0.f};
        for (int j = start + lane; j < end; j += 64) {
            int s = col[j];
            float4 a4 = *(const float4*)(as1 + (size_t)s * 4);
            ds.x += expc(leaky02(a4.x + ad4.x));
            ds.y += expc(leaky02(a4.y + ad4.y));
            ds.z += expc(leaky02(a4.z + ad4.z));
            ds.w += expc(leaky02(a4.w + ad4.w));
        }
#pragma unroll
        for (int sft = 1; sft < 64; sft <<= 1) {
            ds.x += __shfl_xor(ds.x, sft);
            ds.y += __shfl_xor(ds.y, sft);
            ds.z += __shfl_xor(ds.z, sft);
            ds.w += __shfl_xor(ds.w, sft);
        }
        const float dh  = (hch == 0) ? ds.x : (hch == 1) ? ds.y : (hch == 2) ? ds.z : ds.w;
        const float adh = (hch == 0) ? ad4.x : (hch == 1) ? ad4.y : (hch == 2) ? ad4.z : ad4.w;
        const float rdh = 1.f / (dh + 1e-16f);
        float acc[8] = {0.f,0.f,0.f,0.f,0.f,0.f,0.f,0.f};
        for (int j = start + q; j < end; j += 4) {
            int s = col[j];
            float asv = as1[(size_t)s * 4 + hch];
            float alpha = expc(leaky02(asv + adh)) * rdh;
            uint4 hv = *(const uint4*)(h1b + (size_t)s * 128 + cl8 * 8);
            acc[0] = fmaf(alpha, bflo(hv.x), acc[0]);
            acc[1] = fmaf(alpha, bfhi(hv.x), acc[1]);
            acc[2] = fmaf(alpha, bflo(hv.y), acc[2]);
            acc[3] = fmaf(alpha, bfhi(hv.y), acc[3]);
            acc[4] = fmaf(alpha, bflo(hv.z), acc[4]);
            acc[5] = fmaf(alpha, bfhi(hv.z), acc[5]);
            acc[6] = fmaf(alpha, bflo(hv.w), acc[6]);
            acc[7] = fmaf(alpha, bfhi(hv.w), acc[7]);
        }
#pragma unroll
        for (int i = 0; i < 8; ++i) {
            acc[i] += __shfl_xor(acc[i], 16);
            acc[i] += __shfl_xor(acc[i], 32);
        }
        if (q == 0) {
            float4 bv0 = *(const float4*)(b1 + cl8 * 8);
            float4 bv1 = *(const float4*)(b1 + cl8 * 8 + 4);
            float4 o0, o1;
            o0.x = eluf(acc[0] + bv0.x);
            o0.y = eluf(acc[1] + bv0.y);
            o0.z = eluf(acc[2] + bv0.z);
            o0.w = eluf(acc[3] + bv0.w);
            o1.x = eluf(acc[4] + bv1.x);
            o1.y = eluf(acc[5] + bv1.y);
            o1.z = eluf(acc[6] + bv1.z);
            o1.w = eluf(acc[7] + bv1.w);
            *(float4*)(out1 + (size_t)n * 128 + cl8 * 8)     = o0;
            *(float4*)(out1 + (size_t)n * 128 + cl8 * 8 + 4) = o1;
        }
    }
}

// ---------------- GEMM2: z2 = out1 @ w2 (+ as2/ad2) ----------------
__global__ __launch_bounds__(256, 2) void k_gemm2(
    const float* __restrict__ out1, const float* __restrict__ w2,
    const float* __restrict__ a2s, const float* __restrict__ a2d,
    float* __restrict__ z2, float* __restrict__ as2, float* __restrict__ ad2, int N)
{
    __shared__ float xs[128 * 128];
    __shared__ float wsh[128 * 32];
    const int tid = threadIdx.x;
    const int r_base = blockIdx.x * 128;

    for (int i = tid; i < 1024; i += 256) {
        int k = i >> 3, c4 = i & 7;
        float4 v = *(const float4*)(w2 + k * 32 + c4 * 4);
        *(float4*)(wsh + k * 32 + c4 * 4) = v;
    }
    for (int i = tid; i < 4096; i += 256) {
        int r = i >> 5, k4 = i & 31;
        int rr = r_base + r; if (rr >= N) rr = N - 1;
        float4 v = *(const float4*)(out1 + (size_t)rr * 128 + k4 * 4);
        *(float4*)(xs + r * 128 + (k4 ^ (r & 7)) * 4) = v;
    }
    __syncthreads();

    const int c0 = (tid & 7) * 4;
    const int r0 = (tid >> 3) * 4;
    const int swz0 = ((r0 + 0) & 7) << 2;
    const int swz1 = ((r0 + 1) & 7) << 2;
    const int swz2 = ((r0 + 2) & 7) << 2;
    const int swz3 = ((r0 + 3) & 7) << 2;
    const float* xb0 = xs + (r0 + 0) * 128;
    const float* xb1 = xs + (r0 + 1) * 128;
    const float* xb2 = xs + (r0 + 2) * 128;
    const float* xb3 = xs + (r0 + 3) * 128;

    float4 acc0 = {0,0,0,0}, acc1 = {0,0,0,0}, acc2 = {0,0,0,0}, acc3 = {0,0,0,0};
#pragma unroll 4
    for (int k = 0; k < 128; ++k) {
        float4 wv = *(const float4*)(wsh + k * 32 + c0);
        float x0 = xb0[k ^ swz0];
        float x1 = xb1[k ^ swz1];
        float x2 = xb2[k ^ swz2];
        float x3 = xb3[k ^ swz3];
        acc0.x = fmaf(x0, wv.x, acc0.x); acc0.y = fmaf(x0, wv.y, acc0.y);
        acc0.z = fmaf(x0, wv.z, acc0.z); acc0.w = fmaf(x0, wv.w, acc0.w);
        acc1.x = fmaf(x1, wv.x, acc1.x); acc1.y = fmaf(x1, wv.y, acc1.y);
        acc1.z = fmaf(x1, wv.z, acc1.z); acc1.w = fmaf(x1, wv.w, acc1.w);
        acc2.x = fmaf(x2, wv.x, acc2.x); acc2.y = fmaf(x2, wv.y, acc2.y);
        acc2.z = fmaf(x2, wv.z, acc2.z); acc2.w = fmaf(x2, wv.w, acc2.w);
        acc3.x = fmaf(x3, wv.x, acc3.x); acc3.y = fmaf(x3, wv.y, acc3.y);
        acc3.z = fmaf(x3, wv.z, acc3.z); acc3.w = fmaf(x3, wv.w, acc3.w);
    }

    const float4 avs = *(const float4*)(a2s + c0);
    const float4 avd = *(const float4*)(a2d + c0);
    float4 accs[4] = {acc0, acc1, acc2, acc3};
#pragma unroll
    for (int i = 0; i < 4; ++i) {
        int r = r_base + r0 + i;
        float4 a = accs[i];
        float ps = a.x * avs.x + a.y * avs.y + a.z * avs.z + a.w * avs.w;
        float pd = a.x * avd.x + a.y * avd.y + a.z * avd.z + a.w * avd.w;
        ps += __shfl_xor(ps, 1); pd += __shfl_xor(pd, 1);
        ps += __shfl_xor(ps, 2); pd += __shfl_xor(pd, 2);
        ps += __shfl_xor(ps, 4); pd += __shfl_xor(pd, 4);
        if (r < N) {
            *(float4*)(z2 + (size_t)r * 32 + c0) = a;
            if ((tid & 7) == 0) { as2[r] = ps; ad2[r] = pd; }
        }
    }
}

// ---------------- layer-2 aggregation + final linear (wave per dst node) ----------------
__global__ __launch_bounds__(256) void k_agg2(
    const int* __restrict__ rowp, const int* __restrict__ col,
    const float* __restrict__ as2, const float* __restrict__ ad2,
    const float* __restrict__ z2, const float* __restrict__ b2,
    const float* __restrict__ wl, const float* __restrict__ bl,
    float* __restrict__ out, int N)
{
    const int lane = threadIdx.x & 63;
    const int wid  = (blockIdx.x * 256 + threadIdx.x) >> 6;
    const int nw   = (gridDim.x * 256) >> 6;
    const int q  = lane >> 4;
    const int cl = lane & 15;
    for (int n = wid; n < N; n += nw) {
        const int start = rowp[n], end = rowp[n + 1];
        const float adn = ad2[n];
        float d = 0.f;
        for (int j = start + lane; j < end; j += 64) {
            int s = col[j];
            d += expc(leaky02(as2[s] + adn));
        }
#pragma unroll
        for (int sft = 1; sft < 64; sft <<= 1) d += __shfl_xor(d, sft);
        const float rd = 1.f / (d + 1e-16f);
        float2 acc = {0.f, 0.f};
        for (int j = start + q; j < end; j += 4) {
            int s = col[j];
            float alpha = expc(leaky02(as2[s] + adn)) * rd;
            float2 zv = *(const float2*)(z2 + (size_t)s * 32 + cl * 2);
            acc.x = fmaf(alpha, zv.x, acc.x);
            acc.y = fmaf(alpha, zv.y, acc.y);
        }
        acc.x += __shfl_xor(acc.x, 16); acc.y += __shfl_xor(acc.y, 16);
        acc.x += __shfl_xor(acc.x, 32); acc.y += __shfl_xor(acc.y, 32);
        float h0 = eluf(acc.x + b2[cl * 2]);
        float h1v = eluf(acc.y + b2[cl * 2 + 1]);
        float p = h0 * wl[cl * 2] + h1v * wl[cl * 2 + 1];
#pragma unroll
        for (int sft = 1; sft < 16; sft <<= 1) p += __shfl_xor(p, sft);
        if (lane == 0) out[n] = p + bl[0];
    }
}

extern "C" void kernel_launch(void* const* d_in, const int* in_sizes, int n_in,
                              void* d_out, int out_size, void* d_ws, size_t ws_size,
                              hipStream_t stream) {
    const float* x   = (const float*)d_in[0];
    const int*   ei  = (const int*)d_in[1];
    const float* w1  = (const float*)d_in[2];
    const float* a1s = (const float*)d_in[3];
    const float* a1d = (const float*)d_in[4];
    const float* b1  = (const float*)d_in[5];
    const float* w2  = (const float*)d_in[6];
    const float* a2s = (const float*)d_in[7];
    const float* a2d = (const float*)d_in[8];
    const float* b2  = (const float*)d_in[9];
    const float* wl  = (const float*)d_in[10];
    const float* bl  = (const float*)d_in[11];
    float* out = (float*)d_out;

    const int N   = in_sizes[0] / 128;
    const int E   = in_sizes[1] / 2;
    const int Et  = E + N;
    const int NB  = (N + 1023) / 1024;
    const int NBk = (N + 127) / 128;

    float* ws   = (float*)d_ws;
    unsigned short* h1b = (unsigned short*)ws;  // N*128 bf16 = N*64 float slots
    float* out1 = ws   + (size_t)N * 64;        // N*128
    float* as1  = out1 + (size_t)N * 128;       // N*4
    float* ad1  = as1  + (size_t)N * 4;         // N*4
    float* z2   = ad1  + (size_t)N * 4;         // N*32
    float* as2  = z2   + (size_t)N * 32;        // N
    float* ad2  = as2  + N;                     // N
    int* counts = (int*)(ad2 + N);              // N
    int* rowp   = counts + N;                   // N+1
    int* col    = rowp + (N + 1);               // Et
    int* bsum   = col + Et;                     // NB
    int* boff   = bsum + NB;                    // NB
    int* bq     = boff + NB;                    // NBk
    // 8B-align ebuf
    uintptr_t ebase = (uintptr_t)(bq + NBk);
    ebase = (ebase + 7) & ~(uintptr_t)7;
    int2* ebuf  = (int2*)ebase;                 // Et int2

    k_init1<<<(N + 255) / 256, 256, 0, stream>>>(counts, N);
    k_gemm1<<<2 * ((N + 63) / 64), 256, 0, stream>>>(x, w1, a1s, a1d, h1b, as1, ad1, N);
    k_hist<<<(E + 255) / 256, 256, 0, stream>>>(ei, counts, E);
    k_bsum<<<NB, 256, 0, stream>>>(counts, bsum, N);
    k_scansums<<<1, 1024, 0, stream>>>(bsum, boff, rowp + N, NB);
    k_scatter<<<NB, 256, 0, stream>>>(counts, boff, rowp, N);
    k_binit<<<1, 1024, 0, stream>>>(rowp, bq, NBk);
    k_bucket<<<(Et + 255) / 256, 256, 0, stream>>>(ei, bq, ebuf, E, Et);
    k_csort<<<NBk, 256, 0, stream>>>(rowp, ebuf, col, N);
    k_agg1<<<4096, 256, 0, stream>>>(rowp, col, as1, ad1, h1b, b1, out1, N);
    k_gemm2<<<(N + 127) / 128, 256, 0, stream>>>(out1, w2, a2s, a2d, z2, as2, ad2, N);
    k_agg2<<<4096, 256, 0, stream>>>(rowp, col, as2, ad2, z2, b2, wl, bl, out, N);
}

// Round 13
// 582.528 us; speedup vs baseline: 1.5389x; 1.5389x over previous
//
#include <hip/hip_runtime.h>
#include <math.h>

__device__ __forceinline__ float leaky02(float v) { return v > 0.f ? v : 0.2f * v; }
__device__ __forceinline__ float eluf(float v) { return v > 0.f ? v : __expf(v) - 1.f; }
__device__ __forceinline__ float expc(float v) { return __expf(fminf(v, 60.f)); }
// bf16 pack/unpack (RNE)
__device__ __forceinline__ unsigned short f2bf(float f) {
    unsigned int u = __float_as_uint(f);
    return (unsigned short)((u + 0x7FFFu + ((u >> 16) & 1u)) >> 16);
}
__device__ __forceinline__ float bflo(unsigned int u) { return __uint_as_float(u << 16); }
__device__ __forceinline__ float bfhi(unsigned int u) { return __uint_as_float(u & 0xFFFF0000u); }

// ---------------- init counts to 1 (self-loop per node) ----------------
__global__ __launch_bounds__(256) void k_init1(int* __restrict__ p, int n) {
    int t = blockIdx.x * 256 + threadIdx.x;
    if (t < n) p[t] = 1;
}

// ---------------- GEMM1: h1(bf16) = x @ w1 (+ as1/ad1) ----------------
__global__ __launch_bounds__(256, 2) void k_gemm1(
    const float* __restrict__ x, const float* __restrict__ w1,
    const float* __restrict__ a1s, const float* __restrict__ a1d,
    unsigned short* __restrict__ h1b, float* __restrict__ as1, float* __restrict__ ad1, int N)
{
    __shared__ float xs[64 * 128];   // 32 KB, swizzled
    __shared__ float wsh[128 * 64];  // 32 KB
    const int half = blockIdx.x & 1;
    const int tile = blockIdx.x >> 1;
    const int tid  = threadIdx.x;
    const int r_base = tile * 64;

    for (int i = tid; i < 2048; i += 256) {
        int k = i >> 4, c4 = i & 15;
        float4 v = *(const float4*)(w1 + k * 128 + half * 64 + c4 * 4);
        *(float4*)(wsh + k * 64 + c4 * 4) = v;
    }
    for (int i = tid; i < 2048; i += 256) {
        int r = i >> 5, k4 = i & 31;
        int rr = r_base + r; if (rr >= N) rr = N - 1;
        float4 v = *(const float4*)(x + (size_t)rr * 128 + k4 * 4);
        *(float4*)(xs + r * 128 + (k4 ^ (r & 7)) * 4) = v;
    }
    __syncthreads();

    const int c0 = (tid & 15) * 4;
    const int r0 = (tid >> 4) * 4;
    const int swz0 = ((r0 + 0) & 7) << 2;
    const int swz1 = ((r0 + 1) & 7) << 2;
    const int swz2 = ((r0 + 2) & 7) << 2;
    const int swz3 = ((r0 + 3) & 7) << 2;
    const float* xb0 = xs + (r0 + 0) * 128;
    const float* xb1 = xs + (r0 + 1) * 128;
    const float* xb2 = xs + (r0 + 2) * 128;
    const float* xb3 = xs + (r0 + 3) * 128;

    float4 acc0 = {0,0,0,0}, acc1 = {0,0,0,0}, acc2 = {0,0,0,0}, acc3 = {0,0,0,0};
#pragma unroll 4
    for (int k = 0; k < 128; ++k) {
        float4 wv = *(const float4*)(wsh + k * 64 + c0);
        float x0 = xb0[k ^ swz0];
        float x1 = xb1[k ^ swz1];
        float x2 = xb2[k ^ swz2];
        float x3 = xb3[k ^ swz3];
        acc0.x = fmaf(x0, wv.x, acc0.x); acc0.y = fmaf(x0, wv.y, acc0.y);
        acc0.z = fmaf(x0, wv.z, acc0.z); acc0.w = fmaf(x0, wv.w, acc0.w);
        acc1.x = fmaf(x1, wv.x, acc1.x); acc1.y = fmaf(x1, wv.y, acc1.y);
        acc1.z = fmaf(x1, wv.z, acc1.z); acc1.w = fmaf(x1, wv.w, acc1.w);
        acc2.x = fmaf(x2, wv.x, acc2.x); acc2.y = fmaf(x2, wv.y, acc2.y);
        acc2.z = fmaf(x2, wv.z, acc2.z); acc2.w = fmaf(x2, wv.w, acc2.w);
        acc3.x = fmaf(x3, wv.x, acc3.x); acc3.y = fmaf(x3, wv.y, acc3.y);
        acc3.z = fmaf(x3, wv.z, acc3.z); acc3.w = fmaf(x3, wv.w, acc3.w);
    }

    const int cg = half * 64 + c0;
    const float4 avs = *(const float4*)(a1s + cg);
    const float4 avd = *(const float4*)(a1d + cg);
    const int head = half * 2 + ((tid & 15) >> 3);
    float4 accs[4] = {acc0, acc1, acc2, acc3};
#pragma unroll
    for (int i = 0; i < 4; ++i) {
        int r = r_base + r0 + i;
        float4 a = accs[i];
        float ps = a.x * avs.x + a.y * avs.y + a.z * avs.z + a.w * avs.w;
        float pd = a.x * avd.x + a.y * avd.y + a.z * avd.z + a.w * avd.w;
        ps += __shfl_xor(ps, 1); pd += __shfl_xor(pd, 1);
        ps += __shfl_xor(ps, 2); pd += __shfl_xor(pd, 2);
        ps += __shfl_xor(ps, 4); pd += __shfl_xor(pd, 4);
        if (r < N) {
            ushort4 hb;
            hb.x = f2bf(a.x); hb.y = f2bf(a.y); hb.z = f2bf(a.z); hb.w = f2bf(a.w);
            *(ushort4*)(h1b + (size_t)r * 128 + cg) = hb;
            if ((tid & 7) == 0) {
                as1[(size_t)r * 4 + head] = ps;
                ad1[(size_t)r * 4 + head] = pd;
            }
        }
    }
}

// ---------------- CSR build ----------------
__global__ __launch_bounds__(256) void k_hist(const int* __restrict__ ei, int* __restrict__ counts,
                                              int E) {
    int t = blockIdx.x * 256 + threadIdx.x;
    if (t >= E) return;
    atomicAdd(&counts[ei[E + t]], 1);
}

__global__ __launch_bounds__(256) void k_bsum(const int* __restrict__ counts,
                                              int* __restrict__ bsum, int N) {
    int t = threadIdx.x;
    int base = blockIdx.x * 1024 + t * 4;
    int s = 0;
    if (base + 3 < N) { int4 v = *(const int4*)(counts + base); s = v.x + v.y + v.z + v.w; }
    else { for (int j = 0; j < 4; ++j) if (base + j < N) s += counts[base + j]; }
#pragma unroll
    for (int off = 1; off < 64; off <<= 1) s += __shfl_xor(s, off);
    __shared__ int wt[4];
    if ((t & 63) == 0) wt[t >> 6] = s;
    __syncthreads();
    if (t == 0) bsum[blockIdx.x] = wt[0] + wt[1] + wt[2] + wt[3];
}

__global__ __launch_bounds__(1024) void k_scansums(const int* __restrict__ bsum,
                                                   int* __restrict__ boff,
                                                   int* __restrict__ rowp_last, int NB) {
    __shared__ int ps[1024];
    int t = threadIdx.x;
    int v = (t < NB) ? bsum[t] : 0;
    ps[t] = v;
    __syncthreads();
    for (int off = 1; off < 1024; off <<= 1) {
        int u = (t >= off) ? ps[t - off] : 0;
        __syncthreads();
        ps[t] += u;
        __syncthreads();
    }
    if (t < NB) boff[t] = ps[t] - v;
    if (t == NB - 1) *rowp_last = ps[t];
}

__global__ __launch_bounds__(256) void k_scatter(const int* __restrict__ counts,
                                                 const int* __restrict__ boff,
                                                 int* __restrict__ rowp, int* __restrict__ pos, int N) {
    int t = threadIdx.x;
    int lane = t & 63, wv = t >> 6;
    int base = blockIdx.x * 1024 + t * 4;
    int c0 = 0, c1 = 0, c2 = 0, c3 = 0;
    if (base + 3 < N) { int4 v = *(const int4*)(counts + base); c0 = v.x; c1 = v.y; c2 = v.z; c3 = v.w; }
    else {
        if (base     < N) c0 = counts[base];
        if (base + 1 < N) c1 = counts[base + 1];
        if (base + 2 < N) c2 = counts[base + 2];
        if (base + 3 < N) c3 = counts[base + 3];
    }
    int ts = c0 + c1 + c2 + c3;
    int inc = ts;
#pragma unroll
    for (int off = 1; off < 64; off <<= 1) { int u = __shfl_up(inc, off); if (lane >= off) inc += u; }
    int excl = inc - ts;
    __shared__ int wt[4];
    if (lane == 63) wt[wv] = inc;
    __syncthreads();
    int woff = 0;
    for (int i = 0; i < wv; ++i) woff += wt[i];
    int p = boff[blockIdx.x] + woff + excl;
    if (base     < N) { rowp[base]     = p; pos[base]     = p; p += c0; }
    if (base + 1 < N) { rowp[base + 1] = p; pos[base + 1] = p; p += c1; }
    if (base + 2 < N) { rowp[base + 2] = p; pos[base + 2] = p; p += c2; }
    if (base + 3 < N) { rowp[base + 3] = p; pos[base + 3] = p; p += c3; }
}

// fill CSR: col only (4B/edge scatter, nontemporal store)
__global__ __launch_bounds__(256) void k_fill(
    const int* __restrict__ ei, int* __restrict__ pos,
    int* __restrict__ col, int E, int Et)
{
    int t = blockIdx.x * 256 + threadIdx.x;
    if (t >= Et) return;
    int s, dd;
    if (t < E) { s = ei[t]; dd = ei[E + t]; } else { s = dd = t - E; }
    int p = atomicAdd(&pos[dd], 1);
    __builtin_nontemporal_store(s, &col[p]);
}

// ---------------- layer-1 aggregation (wave per dst node) ----------------
__global__ __launch_bounds__(256) void k_agg1(
    const int* __restrict__ rowp, const int* __restrict__ col,
    const float* __restrict__ as1, const float* __restrict__ ad1,
    const unsigned short* __restrict__ h1b,
    const float* __restrict__ b1, float* __restrict__ out1, int N)
{
    const int lane = threadIdx.x & 63;
    const int wid  = (blockIdx.x * 256 + threadIdx.x) >> 6;
    const int nw   = (gridDim.x * 256) >> 6;
    const int q    = lane >> 4;      // 0..3: edge slot
    const int cl8  = lane & 15;      // owns channels cl8*8 .. cl8*8+7
    const int hch  = cl8 >> 2;       // head of this channel group
    for (int n = wid; n < N; n += nw) {
        const int start = rowp[n], end = rowp[n + 1];
        const float4 ad4 = *(const float4*)(ad1 + (size_t)n * 4);
        float4 ds = {0.f, 0.f, 0.f, 0.f};
        for (int j = start + lane; j < end; j += 64) {
            int s = col[j];
            float4 a4 = *(const float4*)(as1 + (size_t)s * 4);
            ds.x += expc(leaky02(a4.x + ad4.x));
            ds.y += expc(leaky02(a4.y + ad4.y));
            ds.z += expc(leaky02(a4.z + ad4.z));
            ds.w += expc(leaky02(a4.w + ad4.w));
        }
#pragma unroll
        for (int sft = 1; sft < 64; sft <<= 1) {
            ds.x += __shfl_xor(ds.x, sft);
            ds.y += __shfl_xor(ds.y, sft);
            ds.z += __shfl_xor(ds.z, sft);
            ds.w += __shfl_xor(ds.w, sft);
        }
        const float dh  = (hch == 0) ? ds.x : (hch == 1) ? ds.y : (hch == 2) ? ds.z : ds.w;
        const float adh = (hch == 0) ? ad4.x : (hch == 1) ? ad4.y : (hch == 2) ? ad4.z : ad4.w;
        const float rdh = 1.f / (dh + 1e-16f);
        float acc[8] = {0.f,0.f,0.f,0.f,0.f,0.f,0.f,0.f};
        for (int j = start + q; j < end; j += 4) {
            int s = col[j];
            float asv = as1[(size_t)s * 4 + hch];
            float alpha = expc(leaky02(asv + adh)) * rdh;
            uint4 hv = *(const uint4*)(h1b + (size_t)s * 128 + cl8 * 8);
            acc[0] = fmaf(alpha, bflo(hv.x), acc[0]);
            acc[1] = fmaf(alpha, bfhi(hv.x), acc[1]);
            acc[2] = fmaf(alpha, bflo(hv.y), acc[2]);
            acc[3] = fmaf(alpha, bfhi(hv.y), acc[3]);
            acc[4] = fmaf(alpha, bflo(hv.z), acc[4]);
            acc[5] = fmaf(alpha, bfhi(hv.z), acc[5]);
            acc[6] = fmaf(alpha, bflo(hv.w), acc[6]);
            acc[7] = fmaf(alpha, bfhi(hv.w), acc[7]);
        }
#pragma unroll
        for (int i = 0; i < 8; ++i) {
            acc[i] += __shfl_xor(acc[i], 16);
            acc[i] += __shfl_xor(acc[i], 32);
        }
        if (q == 0) {
            float4 bv0 = *(const float4*)(b1 + cl8 * 8);
            float4 bv1 = *(const float4*)(b1 + cl8 * 8 + 4);
            float4 o0, o1;
            o0.x = eluf(acc[0] + bv0.x);
            o0.y = eluf(acc[1] + bv0.y);
            o0.z = eluf(acc[2] + bv0.z);
            o0.w = eluf(acc[3] + bv0.w);
            o1.x = eluf(acc[4] + bv1.x);
            o1.y = eluf(acc[5] + bv1.y);
            o1.z = eluf(acc[6] + bv1.z);
            o1.w = eluf(acc[7] + bv1.w);
            *(float4*)(out1 + (size_t)n * 128 + cl8 * 8)     = o0;
            *(float4*)(out1 + (size_t)n * 128 + cl8 * 8 + 4) = o1;
        }
    }
}

// ---------------- GEMM2: z2(bf16) = out1 @ w2 (+ as2/ad2) ----------------
__global__ __launch_bounds__(256, 2) void k_gemm2(
    const float* __restrict__ out1, const float* __restrict__ w2,
    const float* __restrict__ a2s, const float* __restrict__ a2d,
    unsigned short* __restrict__ z2b, float* __restrict__ as2, float* __restrict__ ad2, int N)
{
    __shared__ float xs[128 * 128];
    __shared__ float wsh[128 * 32];
    const int tid = threadIdx.x;
    const int r_base = blockIdx.x * 128;

    for (int i = tid; i < 1024; i += 256) {
        int k = i >> 3, c4 = i & 7;
        float4 v = *(const float4*)(w2 + k * 32 + c4 * 4);
        *(float4*)(wsh + k * 32 + c4 * 4) = v;
    }
    for (int i = tid; i < 4096; i += 256) {
        int r = i >> 5, k4 = i & 31;
        int rr = r_base + r; if (rr >= N) rr = N - 1;
        float4 v = *(const float4*)(out1 + (size_t)rr * 128 + k4 * 4);
        *(float4*)(xs + r * 128 + (k4 ^ (r & 7)) * 4) = v;
    }
    __syncthreads();

    const int c0 = (tid & 7) * 4;
    const int r0 = (tid >> 3) * 4;
    const int swz0 = ((r0 + 0) & 7) << 2;
    const int swz1 = ((r0 + 1) & 7) << 2;
    const int swz2 = ((r0 + 2) & 7) << 2;
    const int swz3 = ((r0 + 3) & 7) << 2;
    const float* xb0 = xs + (r0 + 0) * 128;
    const float* xb1 = xs + (r0 + 1) * 128;
    const float* xb2 = xs + (r0 + 2) * 128;
    const float* xb3 = xs + (r0 + 3) * 128;

    float4 acc0 = {0,0,0,0}, acc1 = {0,0,0,0}, acc2 = {0,0,0,0}, acc3 = {0,0,0,0};
#pragma unroll 4
    for (int k = 0; k < 128; ++k) {
        float4 wv = *(const float4*)(wsh + k * 32 + c0);
        float x0 = xb0[k ^ swz0];
        float x1 = xb1[k ^ swz1];
        float x2 = xb2[k ^ swz2];
        float x3 = xb3[k ^ swz3];
        acc0.x = fmaf(x0, wv.x, acc0.x); acc0.y = fmaf(x0, wv.y, acc0.y);
        acc0.z = fmaf(x0, wv.z, acc0.z); acc0.w = fmaf(x0, wv.w, acc0.w);
        acc1.x = fmaf(x1, wv.x, acc1.x); acc1.y = fmaf(x1, wv.y, acc1.y);
        acc1.z = fmaf(x1, wv.z, acc1.z); acc1.w = fmaf(x1, wv.w, acc1.w);
        acc2.x = fmaf(x2, wv.x, acc2.x); acc2.y = fmaf(x2, wv.y, acc2.y);
        acc2.z = fmaf(x2, wv.z, acc2.z); acc2.w = fmaf(x2, wv.w, acc2.w);
        acc3.x = fmaf(x3, wv.x, acc3.x); acc3.y = fmaf(x3, wv.y, acc3.y);
        acc3.z = fmaf(x3, wv.z, acc3.z); acc3.w = fmaf(x3, wv.w, acc3.w);
    }

    const float4 avs = *(const float4*)(a2s + c0);
    const float4 avd = *(const float4*)(a2d + c0);
    float4 accs[4] = {acc0, acc1, acc2, acc3};
#pragma unroll
    for (int i = 0; i < 4; ++i) {
        int r = r_base + r0 + i;
        float4 a = accs[i];
        float ps = a.x * avs.x + a.y * avs.y + a.z * avs.z + a.w * avs.w;
        float pd = a.x * avd.x + a.y * avd.y + a.z * avd.z + a.w * avd.w;
        ps += __shfl_xor(ps, 1); pd += __shfl_xor(pd, 1);
        ps += __shfl_xor(ps, 2); pd += __shfl_xor(pd, 2);
        ps += __shfl_xor(ps, 4); pd += __shfl_xor(pd, 4);
        if (r < N) {
            ushort4 zb;
            zb.x = f2bf(a.x); zb.y = f2bf(a.y); zb.z = f2bf(a.z); zb.w = f2bf(a.w);
            *(ushort4*)(z2b + (size_t)r * 32 + c0) = zb;
            if ((tid & 7) == 0) { as2[r] = ps; ad2[r] = pd; }
        }
    }
}

// ---------------- layer-2 aggregation + final linear (wave per dst node) ----------------
__global__ __launch_bounds__(256) void k_agg2(
    const int* __restrict__ rowp, const int* __restrict__ col,
    const float* __restrict__ as2, const float* __restrict__ ad2,
    const unsigned short* __restrict__ z2b, const float* __restrict__ b2,
    const float* __restrict__ wl, const float* __restrict__ bl,
    float* __restrict__ out, int N)
{
    const int lane = threadIdx.x & 63;
    const int wid  = (blockIdx.x * 256 + threadIdx.x) >> 6;
    const int nw   = (gridDim.x * 256) >> 6;
    const int q  = lane >> 4;
    const int cl = lane & 15;
    for (int n = wid; n < N; n += nw) {
        const int start = rowp[n], end = rowp[n + 1];
        const float adn = ad2[n];
        float d = 0.f;
        for (int j = start + lane; j < end; j += 64) {
            int s = col[j];
            d += expc(leaky02(as2[s] + adn));
        }
#pragma unroll
        for (int sft = 1; sft < 64; sft <<= 1) d += __shfl_xor(d, sft);
        const float rd = 1.f / (d + 1e-16f);
        float2 acc = {0.f, 0.f};
        for (int j = start + q; j < end; j += 4) {
            int s = col[j];
            float alpha = expc(leaky02(as2[s] + adn)) * rd;
            unsigned int zv = *(const unsigned int*)(z2b + (size_t)s * 32 + cl * 2);
            acc.x = fmaf(alpha, bflo(zv), acc.x);
            acc.y = fmaf(alpha, bfhi(zv), acc.y);
        }
        acc.x += __shfl_xor(acc.x, 16); acc.y += __shfl_xor(acc.y, 16);
        acc.x += __shfl_xor(acc.x, 32); acc.y += __shfl_xor(acc.y, 32);
        float h0 = eluf(acc.x + b2[cl * 2]);
        float h1v = eluf(acc.y + b2[cl * 2 + 1]);
        float p = h0 * wl[cl * 2] + h1v * wl[cl * 2 + 1];
#pragma unroll
        for (int sft = 1; sft < 16; sft <<= 1) p += __shfl_xor(p, sft);
        if (lane == 0) out[n] = p + bl[0];
    }
}

extern "C" void kernel_launch(void* const* d_in, const int* in_sizes, int n_in,
                              void* d_out, int out_size, void* d_ws, size_t ws_size,
                              hipStream_t stream) {
    const float* x   = (const float*)d_in[0];
    const int*   ei  = (const int*)d_in[1];
    const float* w1  = (const float*)d_in[2];
    const float* a1s = (const float*)d_in[3];
    const float* a1d = (const float*)d_in[4];
    const float* b1  = (const float*)d_in[5];
    const float* w2  = (const float*)d_in[6];
    const float* a2s = (const float*)d_in[7];
    const float* a2d = (const float*)d_in[8];
    const float* b2  = (const float*)d_in[9];
    const float* wl  = (const float*)d_in[10];
    const float* bl  = (const float*)d_in[11];
    float* out = (float*)d_out;

    const int N  = in_sizes[0] / 128;
    const int E  = in_sizes[1] / 2;
    const int Et = E + N;
    const int NB = (N + 1023) / 1024;

    float* ws   = (float*)d_ws;
    unsigned short* h1b = (unsigned short*)ws;   // N*128 bf16 = N*64 float slots
    float* out1 = ws   + (size_t)N * 64;         // N*128
    float* as1  = out1 + (size_t)N * 128;        // N*4
    float* ad1  = as1  + (size_t)N * 4;          // N*4
    unsigned short* z2b = (unsigned short*)(ad1 + (size_t)N * 4);  // N*32 bf16 = N*16 float slots
    float* as2  = ad1  + (size_t)N * 4 + (size_t)N * 16;  // N
    float* ad2  = as2  + N;                      // N
    int* counts = (int*)(ad2 + N);               // N
    int* rowp   = counts + N;                    // N+1
    int* col    = rowp + (N + 1);                // Et
    int* pos    = col + Et;                      // N
    int* bsum   = pos + N;                       // NB
    int* boff   = bsum + NB;                     // NB

    k_init1<<<(N + 255) / 256, 256, 0, stream>>>(counts, N);
    k_gemm1<<<2 * ((N + 63) / 64), 256, 0, stream>>>(x, w1, a1s, a1d, h1b, as1, ad1, N);
    k_hist<<<(E + 255) / 256, 256, 0, stream>>>(ei, counts, E);
    k_bsum<<<NB, 256, 0, stream>>>(counts, bsum, N);
    k_scansums<<<1, 1024, 0, stream>>>(bsum, boff, rowp + N, NB);
    k_scatter<<<NB, 256, 0, stream>>>(counts, boff, rowp, pos, N);
    k_fill<<<(Et + 255) / 256, 256, 0, stream>>>(ei, pos, col, E, Et);
    k_agg1<<<4096, 256, 0, stream>>>(rowp, col, as1, ad1, h1b, b1, out1, N);
    k_gemm2<<<(N + 127) / 128, 256, 0, stream>>>(out1, w2, a2s, a2d, z2b, as2, ad2, N);
    k_agg2<<<4096, 256, 0, stream>>>(rowp, col, as2, ad2, z2b, b2, wl, bl, out, N);
}

// Round 14
// 516.563 us; speedup vs baseline: 1.7354x; 1.1277x over previous
//
#include <hip/hip_runtime.h>
#include <math.h>

__device__ __forceinline__ float leaky02(float v) { return v > 0.f ? v : 0.2f * v; }
__device__ __forceinline__ float eluf(float v) { return v > 0.f ? v : __expf(v) - 1.f; }
__device__ __forceinline__ float expc(float v) { return __expf(fminf(v, 60.f)); }
// bf16 pack/unpack (RNE)
__device__ __forceinline__ unsigned short f2bf(float f) {
    unsigned int u = __float_as_uint(f);
    return (unsigned short)((u + 0x7FFFu + ((u >> 16) & 1u)) >> 16);
}
__device__ __forceinline__ float bflo(unsigned int u) { return __uint_as_float(u << 16); }
__device__ __forceinline__ float bfhi(unsigned int u) { return __uint_as_float(u & 0xFFFF0000u); }

// ---------------- init counts to 1 (self-loop per node) ----------------
__global__ __launch_bounds__(256) void k_init1(int* __restrict__ p, int n) {
    int t = blockIdx.x * 256 + threadIdx.x;
    if (t < n) p[t] = 1;
}

// ---------------- GEMM1: h1(bf16) = x @ w1 (+ as1/ad1) ----------------
__global__ __launch_bounds__(256, 2) void k_gemm1(
    const float* __restrict__ x, const float* __restrict__ w1,
    const float* __restrict__ a1s, const float* __restrict__ a1d,
    unsigned short* __restrict__ h1b, float* __restrict__ as1, float* __restrict__ ad1, int N)
{
    __shared__ float xs[64 * 128];   // 32 KB, swizzled
    __shared__ float wsh[128 * 64];  // 32 KB
    const int half = blockIdx.x & 1;
    const int tile = blockIdx.x >> 1;
    const int tid  = threadIdx.x;
    const int r_base = tile * 64;

    for (int i = tid; i < 2048; i += 256) {
        int k = i >> 4, c4 = i & 15;
        float4 v = *(const float4*)(w1 + k * 128 + half * 64 + c4 * 4);
        *(float4*)(wsh + k * 64 + c4 * 4) = v;
    }
    for (int i = tid; i < 2048; i += 256) {
        int r = i >> 5, k4 = i & 31;
        int rr = r_base + r; if (rr >= N) rr = N - 1;
        float4 v = *(const float4*)(x + (size_t)rr * 128 + k4 * 4);
        *(float4*)(xs + r * 128 + (k4 ^ (r & 7)) * 4) = v;
    }
    __syncthreads();

    const int c0 = (tid & 15) * 4;
    const int r0 = (tid >> 4) * 4;
    const int swz0 = ((r0 + 0) & 7) << 2;
    const int swz1 = ((r0 + 1) & 7) << 2;
    const int swz2 = ((r0 + 2) & 7) << 2;
    const int swz3 = ((r0 + 3) & 7) << 2;
    const float* xb0 = xs + (r0 + 0) * 128;
    const float* xb1 = xs + (r0 + 1) * 128;
    const float* xb2 = xs + (r0 + 2) * 128;
    const float* xb3 = xs + (r0 + 3) * 128;

    float4 acc0 = {0,0,0,0}, acc1 = {0,0,0,0}, acc2 = {0,0,0,0}, acc3 = {0,0,0,0};
#pragma unroll 4
    for (int k = 0; k < 128; ++k) {
        float4 wv = *(const float4*)(wsh + k * 64 + c0);
        float x0 = xb0[k ^ swz0];
        float x1 = xb1[k ^ swz1];
        float x2 = xb2[k ^ swz2];
        float x3 = xb3[k ^ swz3];
        acc0.x = fmaf(x0, wv.x, acc0.x); acc0.y = fmaf(x0, wv.y, acc0.y);
        acc0.z = fmaf(x0, wv.z, acc0.z); acc0.w = fmaf(x0, wv.w, acc0.w);
        acc1.x = fmaf(x1, wv.x, acc1.x); acc1.y = fmaf(x1, wv.y, acc1.y);
        acc1.z = fmaf(x1, wv.z, acc1.z); acc1.w = fmaf(x1, wv.w, acc1.w);
        acc2.x = fmaf(x2, wv.x, acc2.x); acc2.y = fmaf(x2, wv.y, acc2.y);
        acc2.z = fmaf(x2, wv.z, acc2.z); acc2.w = fmaf(x2, wv.w, acc2.w);
        acc3.x = fmaf(x3, wv.x, acc3.x); acc3.y = fmaf(x3, wv.y, acc3.y);
        acc3.z = fmaf(x3, wv.z, acc3.z); acc3.w = fmaf(x3, wv.w, acc3.w);
    }

    const int cg = half * 64 + c0;
    const float4 avs = *(const float4*)(a1s + cg);
    const float4 avd = *(const float4*)(a1d + cg);
    const int head = half * 2 + ((tid & 15) >> 3);
    float4 accs[4] = {acc0, acc1, acc2, acc3};
#pragma unroll
    for (int i = 0; i < 4; ++i) {
        int r = r_base + r0 + i;
        float4 a = accs[i];
        float ps = a.x * avs.x + a.y * avs.y + a.z * avs.z + a.w * avs.w;
        float pd = a.x * avd.x + a.y * avd.y + a.z * avd.z + a.w * avd.w;
        ps += __shfl_xor(ps, 1); pd += __shfl_xor(pd, 1);
        ps += __shfl_xor(ps, 2); pd += __shfl_xor(pd, 2);
        ps += __shfl_xor(ps, 4); pd += __shfl_xor(pd, 4);
        if (r < N) {
            ushort4 hb;
            hb.x = f2bf(a.x); hb.y = f2bf(a.y); hb.z = f2bf(a.z); hb.w = f2bf(a.w);
            *(ushort4*)(h1b + (size_t)r * 128 + cg) = hb;
            if ((tid & 7) == 0) {
                as1[(size_t)r * 4 + head] = ps;
                ad1[(size_t)r * 4 + head] = pd;
            }
        }
    }
}

// ---------------- CSR build ----------------
__global__ __launch_bounds__(256) void k_hist(const int* __restrict__ ei, int* __restrict__ counts,
                                              int E) {
    int t = blockIdx.x * 256 + threadIdx.x;
    if (t >= E) return;
    atomicAdd(&counts[ei[E + t]], 1);
}

__global__ __launch_bounds__(256) void k_bsum(const int* __restrict__ counts,
                                              int* __restrict__ bsum, int N) {
    int t = threadIdx.x;
    int base = blockIdx.x * 1024 + t * 4;
    int s = 0;
    if (base + 3 < N) { int4 v = *(const int4*)(counts + base); s = v.x + v.y + v.z + v.w; }
    else { for (int j = 0; j < 4; ++j) if (base + j < N) s += counts[base + j]; }
#pragma unroll
    for (int off = 1; off < 64; off <<= 1) s += __shfl_xor(s, off);
    __shared__ int wt[4];
    if ((t & 63) == 0) wt[t >> 6] = s;
    __syncthreads();
    if (t == 0) bsum[blockIdx.x] = wt[0] + wt[1] + wt[2] + wt[3];
}

__global__ __launch_bounds__(1024) void k_scansums(const int* __restrict__ bsum,
                                                   int* __restrict__ boff,
                                                   int* __restrict__ rowp_last, int NB) {
    __shared__ int ps[1024];
    int t = threadIdx.x;
    int v = (t < NB) ? bsum[t] : 0;
    ps[t] = v;
    __syncthreads();
    for (int off = 1; off < 1024; off <<= 1) {
        int u = (t >= off) ? ps[t - off] : 0;
        __syncthreads();
        ps[t] += u;
        __syncthreads();
    }
    if (t < NB) boff[t] = ps[t] - v;
    if (t == NB - 1) *rowp_last = ps[t];
}

__global__ __launch_bounds__(256) void k_scatter(const int* __restrict__ counts,
                                                 const int* __restrict__ boff,
                                                 int* __restrict__ rowp, int* __restrict__ pos, int N) {
    int t = threadIdx.x;
    int lane = t & 63, wv = t >> 6;
    int base = blockIdx.x * 1024 + t * 4;
    int c0 = 0, c1 = 0, c2 = 0, c3 = 0;
    if (base + 3 < N) { int4 v = *(const int4*)(counts + base); c0 = v.x; c1 = v.y; c2 = v.z; c3 = v.w; }
    else {
        if (base     < N) c0 = counts[base];
        if (base + 1 < N) c1 = counts[base + 1];
        if (base + 2 < N) c2 = counts[base + 2];
        if (base + 3 < N) c3 = counts[base + 3];
    }
    int ts = c0 + c1 + c2 + c3;
    int inc = ts;
#pragma unroll
    for (int off = 1; off < 64; off <<= 1) { int u = __shfl_up(inc, off); if (lane >= off) inc += u; }
    int excl = inc - ts;
    __shared__ int wt[4];
    if (lane == 63) wt[wv] = inc;
    __syncthreads();
    int woff = 0;
    for (int i = 0; i < wv; ++i) woff += wt[i];
    int p = boff[blockIdx.x] + woff + excl;
    if (base     < N) { rowp[base]     = p; pos[base]     = p; p += c0; }
    if (base + 1 < N) { rowp[base + 1] = p; pos[base + 1] = p; p += c1; }
    if (base + 2 < N) { rowp[base + 2] = p; pos[base + 2] = p; p += c2; }
    if (base + 3 < N) { rowp[base + 3] = p; pos[base + 3] = p; p += c3; }
}

// fill CSR, XCD-partitioned: group g = blockIdx&7 commits only dst in its N/8 range,
// so each col/pos line has a single-XCD writer set and stays L2-resident until full.
__global__ __launch_bounds__(256) void k_fill(
    const int* __restrict__ ei, int* __restrict__ pos,
    int* __restrict__ col, int E, int Et, int N)
{
    const int g    = blockIdx.x & 7;
    const int gbid = blockIdx.x >> 3;
    const int ngb  = gridDim.x >> 3;
    const int chunk = (N + 7) >> 3;
    const int lo = g * chunk;
    const int hi = min(N, lo + chunk);
    for (int t = gbid * 256 + threadIdx.x; t < Et; t += ngb * 256) {
        int dd = (t < E) ? ei[E + t] : (t - E);
        if (dd >= lo && dd < hi) {
            int s = (t < E) ? ei[t] : dd;
            int p = atomicAdd(&pos[dd], 1);
            col[p] = s;
        }
    }
}

// ---------------- layer-1 aggregation (wave per dst node) ----------------
__global__ __launch_bounds__(256) void k_agg1(
    const int* __restrict__ rowp, const int* __restrict__ col,
    const float* __restrict__ as1, const float* __restrict__ ad1,
    const unsigned short* __restrict__ h1b,
    const float* __restrict__ b1, float* __restrict__ out1, int N)
{
    const int lane = threadIdx.x & 63;
    const int wid  = (blockIdx.x * 256 + threadIdx.x) >> 6;
    const int nw   = (gridDim.x * 256) >> 6;
    const int q    = lane >> 4;      // 0..3: edge slot
    const int cl8  = lane & 15;      // owns channels cl8*8 .. cl8*8+7
    const int hch  = cl8 >> 2;       // head of this channel group
    for (int n = wid; n < N; n += nw) {
        const int start = rowp[n], end = rowp[n + 1];
        const float4 ad4 = *(const float4*)(ad1 + (size_t)n * 4);
        float4 ds = {0.f, 0.f, 0.f, 0.f};
        for (int j = start + lane; j < end; j += 64) {
            int s = col[j];
            float4 a4 = *(const float4*)(as1 + (size_t)s * 4);
            ds.x += expc(leaky02(a4.x + ad4.x));
            ds.y += expc(leaky02(a4.y + ad4.y));
            ds.z += expc(leaky02(a4.z + ad4.z));
            ds.w += expc(leaky02(a4.w + ad4.w));
        }
#pragma unroll
        for (int sft = 1; sft < 64; sft <<= 1) {
            ds.x += __shfl_xor(ds.x, sft);
            ds.y += __shfl_xor(ds.y, sft);
            ds.z += __shfl_xor(ds.z, sft);
            ds.w += __shfl_xor(ds.w, sft);
        }
        const float dh  = (hch == 0) ? ds.x : (hch == 1) ? ds.y : (hch == 2) ? ds.z : ds.w;
        const float adh = (hch == 0) ? ad4.x : (hch == 1) ? ad4.y : (hch == 2) ? ad4.z : ad4.w;
        const float rdh = 1.f / (dh + 1e-16f);
        float acc[8] = {0.f,0.f,0.f,0.f,0.f,0.f,0.f,0.f};
        for (int j = start + q; j < end; j += 4) {
            int s = col[j];
            float asv = as1[(size_t)s * 4 + hch];
            float alpha = expc(leaky02(asv + adh)) * rdh;
            uint4 hv = *(const uint4*)(h1b + (size_t)s * 128 + cl8 * 8);
            acc[0] = fmaf(alpha, bflo(hv.x), acc[0]);
            acc[1] = fmaf(alpha, bfhi(hv.x), acc[1]);
            acc[2] = fmaf(alpha, bflo(hv.y), acc[2]);
            acc[3] = fmaf(alpha, bfhi(hv.y), acc[3]);
            acc[4] = fmaf(alpha, bflo(hv.z), acc[4]);
            acc[5] = fmaf(alpha, bfhi(hv.z), acc[5]);
            acc[6] = fmaf(alpha, bflo(hv.w), acc[6]);
            acc[7] = fmaf(alpha, bfhi(hv.w), acc[7]);
        }
#pragma unroll
        for (int i = 0; i < 8; ++i) {
            acc[i] += __shfl_xor(acc[i], 16);
            acc[i] += __shfl_xor(acc[i], 32);
        }
        if (q == 0) {
            float4 bv0 = *(const float4*)(b1 + cl8 * 8);
            float4 bv1 = *(const float4*)(b1 + cl8 * 8 + 4);
            float4 o0, o1;
            o0.x = eluf(acc[0] + bv0.x);
            o0.y = eluf(acc[1] + bv0.y);
            o0.z = eluf(acc[2] + bv0.z);
            o0.w = eluf(acc[3] + bv0.w);
            o1.x = eluf(acc[4] + bv1.x);
            o1.y = eluf(acc[5] + bv1.y);
            o1.z = eluf(acc[6] + bv1.z);
            o1.w = eluf(acc[7] + bv1.w);
            *(float4*)(out1 + (size_t)n * 128 + cl8 * 8)     = o0;
            *(float4*)(out1 + (size_t)n * 128 + cl8 * 8 + 4) = o1;
        }
    }
}

// ---------------- GEMM2: z2(bf16) = out1 @ w2 (+ as2/ad2) ----------------
__global__ __launch_bounds__(256, 2) void k_gemm2(
    const float* __restrict__ out1, const float* __restrict__ w2,
    const float* __restrict__ a2s, const float* __restrict__ a2d,
    unsigned short* __restrict__ z2b, float* __restrict__ as2, float* __restrict__ ad2, int N)
{
    __shared__ float xs[128 * 128];
    __shared__ float wsh[128 * 32];
    const int tid = threadIdx.x;
    const int r_base = blockIdx.x * 128;

    for (int i = tid; i < 1024; i += 256) {
        int k = i >> 3, c4 = i & 7;
        float4 v = *(const float4*)(w2 + k * 32 + c4 * 4);
        *(float4*)(wsh + k * 32 + c4 * 4) = v;
    }
    for (int i = tid; i < 4096; i += 256) {
        int r = i >> 5, k4 = i & 31;
        int rr = r_base + r; if (rr >= N) rr = N - 1;
        float4 v = *(const float4*)(out1 + (size_t)rr * 128 + k4 * 4);
        *(float4*)(xs + r * 128 + (k4 ^ (r & 7)) * 4) = v;
    }
    __syncthreads();

    const int c0 = (tid & 7) * 4;
    const int r0 = (tid >> 3) * 4;
    const int swz0 = ((r0 + 0) & 7) << 2;
    const int swz1 = ((r0 + 1) & 7) << 2;
    const int swz2 = ((r0 + 2) & 7) << 2;
    const int swz3 = ((r0 + 3) & 7) << 2;
    const float* xb0 = xs + (r0 + 0) * 128;
    const float* xb1 = xs + (r0 + 1) * 128;
    const float* xb2 = xs + (r0 + 2) * 128;
    const float* xb3 = xs + (r0 + 3) * 128;

    float4 acc0 = {0,0,0,0}, acc1 = {0,0,0,0}, acc2 = {0,0,0,0}, acc3 = {0,0,0,0};
#pragma unroll 4
    for (int k = 0; k < 128; ++k) {
        float4 wv = *(const float4*)(wsh + k * 32 + c0);
        float x0 = xb0[k ^ swz0];
        float x1 = xb1[k ^ swz1];
        float x2 = xb2[k ^ swz2];
        float x3 = xb3[k ^ swz3];
        acc0.x = fmaf(x0, wv.x, acc0.x); acc0.y = fmaf(x0, wv.y, acc0.y);
        acc0.z = fmaf(x0, wv.z, acc0.z); acc0.w = fmaf(x0, wv.w, acc0.w);
        acc1.x = fmaf(x1, wv.x, acc1.x); acc1.y = fmaf(x1, wv.y, acc1.y);
        acc1.z = fmaf(x1, wv.z, acc1.z); acc1.w = fmaf(x1, wv.w, acc1.w);
        acc2.x = fmaf(x2, wv.x, acc2.x); acc2.y = fmaf(x2, wv.y, acc2.y);
        acc2.z = fmaf(x2, wv.z, acc2.z); acc2.w = fmaf(x2, wv.w, acc2.w);
        acc3.x = fmaf(x3, wv.x, acc3.x); acc3.y = fmaf(x3, wv.y, acc3.y);
        acc3.z = fmaf(x3, wv.z, acc3.z); acc3.w = fmaf(x3, wv.w, acc3.w);
    }

    const float4 avs = *(const float4*)(a2s + c0);
    const float4 avd = *(const float4*)(a2d + c0);
    float4 accs[4] = {acc0, acc1, acc2, acc3};
#pragma unroll
    for (int i = 0; i < 4; ++i) {
        int r = r_base + r0 + i;
        float4 a = accs[i];
        float ps = a.x * avs.x + a.y * avs.y + a.z * avs.z + a.w * avs.w;
        float pd = a.x * avd.x + a.y * avd.y + a.z * avd.z + a.w * avd.w;
        ps += __shfl_xor(ps, 1); pd += __shfl_xor(pd, 1);
        ps += __shfl_xor(ps, 2); pd += __shfl_xor(pd, 2);
        ps += __shfl_xor(ps, 4); pd += __shfl_xor(pd, 4);
        if (r < N) {
            ushort4 zb;
            zb.x = f2bf(a.x); zb.y = f2bf(a.y); zb.z = f2bf(a.z); zb.w = f2bf(a.w);
            *(ushort4*)(z2b + (size_t)r * 32 + c0) = zb;
            if ((tid & 7) == 0) { as2[r] = ps; ad2[r] = pd; }
        }
    }
}

// ---------------- layer-2 aggregation + final linear (wave per dst node) ----------------
__global__ __launch_bounds__(256) void k_agg2(
    const int* __restrict__ rowp, const int* __restrict__ col,
    const float* __restrict__ as2, const float* __restrict__ ad2,
    const unsigned short* __restrict__ z2b, const float* __restrict__ b2,
    const float* __restrict__ wl, const float* __restrict__ bl,
    float* __restrict__ out, int N)
{
    const int lane = threadIdx.x & 63;
    const int wid  = (blockIdx.x * 256 + threadIdx.x) >> 6;
    const int nw   = (gridDim.x * 256) >> 6;
    const int q  = lane >> 4;
    const int cl = lane & 15;
    for (int n = wid; n < N; n += nw) {
        const int start = rowp[n], end = rowp[n + 1];
        const float adn = ad2[n];
        float d = 0.f;
        for (int j = start + lane; j < end; j += 64) {
            int s = col[j];
            d += expc(leaky02(as2[s] + adn));
        }
#pragma unroll
        for (int sft = 1; sft < 64; sft <<= 1) d += __shfl_xor(d, sft);
        const float rd = 1.f / (d + 1e-16f);
        float2 acc = {0.f, 0.f};
        for (int j = start + q; j < end; j += 4) {
            int s = col[j];
            float alpha = expc(leaky02(as2[s] + adn)) * rd;
            unsigned int zv = *(const unsigned int*)(z2b + (size_t)s * 32 + cl * 2);
            acc.x = fmaf(alpha, bflo(zv), acc.x);
            acc.y = fmaf(alpha, bfhi(zv), acc.y);
        }
        acc.x += __shfl_xor(acc.x, 16); acc.y += __shfl_xor(acc.y, 16);
        acc.x += __shfl_xor(acc.x, 32); acc.y += __shfl_xor(acc.y, 32);
        float h0 = eluf(acc.x + b2[cl * 2]);
        float h1v = eluf(acc.y + b2[cl * 2 + 1]);
        float p = h0 * wl[cl * 2] + h1v * wl[cl * 2 + 1];
#pragma unroll
        for (int sft = 1; sft < 16; sft <<= 1) p += __shfl_xor(p, sft);
        if (lane == 0) out[n] = p + bl[0];
    }
}

extern "C" void kernel_launch(void* const* d_in, const int* in_sizes, int n_in,
                              void* d_out, int out_size, void* d_ws, size_t ws_size,
                              hipStream_t stream) {
    const float* x   = (const float*)d_in[0];
    const int*   ei  = (const int*)d_in[1];
    const float* w1  = (const float*)d_in[2];
    const float* a1s = (const float*)d_in[3];
    const float* a1d = (const float*)d_in[4];
    const float* b1  = (const float*)d_in[5];
    const float* w2  = (const float*)d_in[6];
    const float* a2s = (const float*)d_in[7];
    const float* a2d = (const float*)d_in[8];
    const float* b2  = (const float*)d_in[9];
    const float* wl  = (const float*)d_in[10];
    const float* bl  = (const float*)d_in[11];
    float* out = (float*)d_out;

    const int N  = in_sizes[0] / 128;
    const int E  = in_sizes[1] / 2;
    const int Et = E + N;
    const int NB = (N + 1023) / 1024;

    float* ws   = (float*)d_ws;
    unsigned short* h1b = (unsigned short*)ws;   // N*128 bf16 = N*64 float slots
    float* out1 = ws   + (size_t)N * 64;         // N*128
    float* as1  = out1 + (size_t)N * 128;        // N*4
    float* ad1  = as1  + (size_t)N * 4;          // N*4
    unsigned short* z2b = (unsigned short*)(ad1 + (size_t)N * 4);  // N*32 bf16 = N*16 float slots
    float* as2  = ad1  + (size_t)N * 4 + (size_t)N * 16;  // N
    float* ad2  = as2  + N;                      // N
    int* counts = (int*)(ad2 + N);               // N
    int* rowp   = counts + N;                    // N+1
    int* col    = rowp + (N + 1);                // Et
    int* pos    = col + Et;                      // N
    int* bsum   = pos + N;                       // NB
    int* boff   = bsum + NB;                     // NB

    k_init1<<<(N + 255) / 256, 256, 0, stream>>>(counts, N);
    k_gemm1<<<2 * ((N + 63) / 64), 256, 0, stream>>>(x, w1, a1s, a1d, h1b, as1, ad1, N);
    k_hist<<<(E + 255) / 256, 256, 0, stream>>>(ei, counts, E);
    k_bsum<<<NB, 256, 0, stream>>>(counts, bsum, N);
    k_scansums<<<1, 1024, 0, stream>>>(bsum, boff, rowp + N, NB);
    k_scatter<<<NB, 256, 0, stream>>>(counts, boff, rowp, pos, N);
    k_fill<<<2048, 256, 0, stream>>>(ei, pos, col, E, Et, N);
    k_agg1<<<4096, 256, 0, stream>>>(rowp, col, as1, ad1, h1b, b1, out1, N);
    k_gemm2<<<(N + 127) / 128, 256, 0, stream>>>(out1, w2, a2s, a2d, z2b, as2, ad2, N);
    k_agg2<<<4096, 256, 0, stream>>>(rowp, col, as2, ad2, z2b, b2, wl, bl, out, N);
}

// Round 16
// 486.832 us; speedup vs baseline: 1.8414x; 1.0611x over previous
//
#include <hip/hip_runtime.h>
#include <math.h>

__device__ __forceinline__ float leaky02(float v) { return v > 0.f ? v : 0.2f * v; }
__device__ __forceinline__ float eluf(float v) { return v > 0.f ? v : __expf(v) - 1.f; }
__device__ __forceinline__ float expc(float v) { return __expf(fminf(v, 60.f)); }
// bf16 pack/unpack (RNE)
__device__ __forceinline__ unsigned short f2bf(float f) {
    unsigned int u = __float_as_uint(f);
    return (unsigned short)((u + 0x7FFFu + ((u >> 16) & 1u)) >> 16);
}
__device__ __forceinline__ float bflo(unsigned int u) { return __uint_as_float(u << 16); }
__device__ __forceinline__ float bfhi(unsigned int u) { return __uint_as_float(u & 0xFFFF0000u); }

#define FMA4(acc, xsc, wv) \
    acc.x = fmaf(xsc, wv.x, acc.x); acc.y = fmaf(xsc, wv.y, acc.y); \
    acc.z = fmaf(xsc, wv.z, acc.z); acc.w = fmaf(xsc, wv.w, acc.w);

// ---------------- init counts to 1 (self-loop per node) ----------------
__global__ __launch_bounds__(256) void k_init1(int* __restrict__ p, int n) {
    int t = blockIdx.x * 256 + threadIdx.x;
    if (t < n) p[t] = 1;
}

// ---------------- GEMM1: h1(bf16) = x @ w1 (+ as1/ad1) ----------------
// inner loop over k4 granules: x read as float4 (swizzled granule = 4 consecutive k)
__global__ __launch_bounds__(256, 2) void k_gemm1(
    const float* __restrict__ x, const float* __restrict__ w1,
    const float* __restrict__ a1s, const float* __restrict__ a1d,
    unsigned short* __restrict__ h1b, float* __restrict__ as1, float* __restrict__ ad1, int N)
{
    __shared__ float xs[64 * 128];   // 32 KB, swizzled
    __shared__ float wsh[128 * 64];  // 32 KB
    const int half = blockIdx.x & 1;
    const int tile = blockIdx.x >> 1;
    const int tid  = threadIdx.x;
    const int r_base = tile * 64;

    for (int i = tid; i < 2048; i += 256) {
        int k = i >> 4, c4 = i & 15;
        float4 v = *(const float4*)(w1 + k * 128 + half * 64 + c4 * 4);
        *(float4*)(wsh + k * 64 + c4 * 4) = v;
    }
    for (int i = tid; i < 2048; i += 256) {
        int r = i >> 5, k4 = i & 31;
        int rr = r_base + r; if (rr >= N) rr = N - 1;
        float4 v = *(const float4*)(x + (size_t)rr * 128 + k4 * 4);
        *(float4*)(xs + r * 128 + (k4 ^ (r & 7)) * 4) = v;
    }
    __syncthreads();

    const int c0 = (tid & 15) * 4;
    const int r0 = (tid >> 4) * 4;
    const int s0 = (r0 + 0) & 7, s1 = (r0 + 1) & 7, s2 = (r0 + 2) & 7, s3 = (r0 + 3) & 7;
    const float* xb0 = xs + (r0 + 0) * 128;
    const float* xb1 = xs + (r0 + 1) * 128;
    const float* xb2 = xs + (r0 + 2) * 128;
    const float* xb3 = xs + (r0 + 3) * 128;

    float4 acc0 = {0,0,0,0}, acc1 = {0,0,0,0}, acc2 = {0,0,0,0}, acc3 = {0,0,0,0};
#pragma unroll 8
    for (int k4 = 0; k4 < 32; ++k4) {
        float4 xv0 = *(const float4*)(xb0 + ((k4 ^ s0) << 2));
        float4 xv1 = *(const float4*)(xb1 + ((k4 ^ s1) << 2));
        float4 xv2 = *(const float4*)(xb2 + ((k4 ^ s2) << 2));
        float4 xv3 = *(const float4*)(xb3 + ((k4 ^ s3) << 2));
        const float* wk = wsh + k4 * 256 + c0;
        float4 w0 = *(const float4*)(wk);
        float4 w1v = *(const float4*)(wk + 64);
        float4 w2 = *(const float4*)(wk + 128);
        float4 w3 = *(const float4*)(wk + 192);
        FMA4(acc0, xv0.x, w0) FMA4(acc1, xv1.x, w0) FMA4(acc2, xv2.x, w0) FMA4(acc3, xv3.x, w0)
        FMA4(acc0, xv0.y, w1v) FMA4(acc1, xv1.y, w1v) FMA4(acc2, xv2.y, w1v) FMA4(acc3, xv3.y, w1v)
        FMA4(acc0, xv0.z, w2) FMA4(acc1, xv1.z, w2) FMA4(acc2, xv2.z, w2) FMA4(acc3, xv3.z, w2)
        FMA4(acc0, xv0.w, w3) FMA4(acc1, xv1.w, w3) FMA4(acc2, xv2.w, w3) FMA4(acc3, xv3.w, w3)
    }

    const int cg = half * 64 + c0;
    const float4 avs = *(const float4*)(a1s + cg);
    const float4 avd = *(const float4*)(a1d + cg);
    const int head = half * 2 + ((tid & 15) >> 3);
    float4 accs[4] = {acc0, acc1, acc2, acc3};
#pragma unroll
    for (int i = 0; i < 4; ++i) {
        int r = r_base + r0 + i;
        float4 a = accs[i];
        float ps = a.x * avs.x + a.y * avs.y + a.z * avs.z + a.w * avs.w;
        float pd = a.x * avd.x + a.y * avd.y + a.z * avd.z + a.w * avd.w;
        ps += __shfl_xor(ps, 1); pd += __shfl_xor(pd, 1);
        ps += __shfl_xor(ps, 2); pd += __shfl_xor(pd, 2);
        ps += __shfl_xor(ps, 4); pd += __shfl_xor(pd, 4);
        if (r < N) {
            ushort4 hb;
            hb.x = f2bf(a.x); hb.y = f2bf(a.y); hb.z = f2bf(a.z); hb.w = f2bf(a.w);
            *(ushort4*)(h1b + (size_t)r * 128 + cg) = hb;
            if ((tid & 7) == 0) {
                as1[(size_t)r * 4 + head] = ps;
                ad1[(size_t)r * 4 + head] = pd;
            }
        }
    }
}

// ---------------- CSR build ----------------
__global__ __launch_bounds__(256) void k_hist(const int* __restrict__ ei, int* __restrict__ counts,
                                              int E) {
    int t = blockIdx.x * 256 + threadIdx.x;
    if (t >= E) return;
    atomicAdd(&counts[ei[E + t]], 1);
}

__global__ __launch_bounds__(256) void k_bsum(const int* __restrict__ counts,
                                              int* __restrict__ bsum, int N) {
    int t = threadIdx.x;
    int base = blockIdx.x * 1024 + t * 4;
    int s = 0;
    if (base + 3 < N) { int4 v = *(const int4*)(counts + base); s = v.x + v.y + v.z + v.w; }
    else { for (int j = 0; j < 4; ++j) if (base + j < N) s += counts[base + j]; }
#pragma unroll
    for (int off = 1; off < 64; off <<= 1) s += __shfl_xor(s, off);
    __shared__ int wt[4];
    if ((t & 63) == 0) wt[t >> 6] = s;
    __syncthreads();
    if (t == 0) bsum[blockIdx.x] = wt[0] + wt[1] + wt[2] + wt[3];
}

__global__ __launch_bounds__(1024) void k_scansums(const int* __restrict__ bsum,
                                                   int* __restrict__ boff,
                                                   int* __restrict__ rowp_last, int NB) {
    __shared__ int ps[1024];
    int t = threadIdx.x;
    int v = (t < NB) ? bsum[t] : 0;
    ps[t] = v;
    __syncthreads();
    for (int off = 1; off < 1024; off <<= 1) {
        int u = (t >= off) ? ps[t - off] : 0;
        __syncthreads();
        ps[t] += u;
        __syncthreads();
    }
    if (t < NB) boff[t] = ps[t] - v;
    if (t == NB - 1) *rowp_last = ps[t];
}

__global__ __launch_bounds__(256) void k_scatter(const int* __restrict__ counts,
                                                 const int* __restrict__ boff,
                                                 int* __restrict__ rowp, int* __restrict__ pos, int N) {
    int t = threadIdx.x;
    int lane = t & 63, wv = t >> 6;
    int base = blockIdx.x * 1024 + t * 4;
    int c0 = 0, c1 = 0, c2 = 0, c3 = 0;
    if (base + 3 < N) { int4 v = *(const int4*)(counts + base); c0 = v.x; c1 = v.y; c2 = v.z; c3 = v.w; }
    else {
        if (base     < N) c0 = counts[base];
        if (base + 1 < N) c1 = counts[base + 1];
        if (base + 2 < N) c2 = counts[base + 2];
        if (base + 3 < N) c3 = counts[base + 3];
    }
    int ts = c0 + c1 + c2 + c3;
    int inc = ts;
#pragma unroll
    for (int off = 1; off < 64; off <<= 1) { int u = __shfl_up(inc, off); if (lane >= off) inc += u; }
    int excl = inc - ts;
    __shared__ int wt[4];
    if (lane == 63) wt[wv] = inc;
    __syncthreads();
    int woff = 0;
    for (int i = 0; i < wv; ++i) woff += wt[i];
    int p = boff[blockIdx.x] + woff + excl;
    if (base     < N) { rowp[base]     = p; pos[base]     = p; p += c0; }
    if (base + 1 < N) { rowp[base + 1] = p; pos[base + 1] = p; p += c1; }
    if (base + 2 < N) { rowp[base + 2] = p; pos[base + 2] = p; p += c2; }
    if (base + 3 < N) { rowp[base + 3] = p; pos[base + 3] = p; p += c3; }
}

// fill CSR, XCD-partitioned (measured win, round 14)
__global__ __launch_bounds__(256) void k_fill(
    const int* __restrict__ ei, int* __restrict__ pos,
    int* __restrict__ col, int E, int Et, int N)
{
    const int g    = blockIdx.x & 7;
    const int gbid = blockIdx.x >> 3;
    const int ngb  = gridDim.x >> 3;
    const int chunk = (N + 7) >> 3;
    const int lo = g * chunk;
    const int hi = min(N, lo + chunk);
    for (int t = gbid * 256 + threadIdx.x; t < Et; t += ngb * 256) {
        int dd = (t < E) ? ei[E + t] : (t - E);
        if (dd >= lo && dd < hi) {
            int s = (t < E) ? ei[t] : dd;
            int p = atomicAdd(&pos[dd], 1);
            col[p] = s;
        }
    }
}

// ---------------- layer-1 aggregation (wave per dst node) ----------------
__global__ __launch_bounds__(256) void k_agg1(
    const int* __restrict__ rowp, const int* __restrict__ col,
    const float* __restrict__ as1, const float* __restrict__ ad1,
    const unsigned short* __restrict__ h1b,
    const float* __restrict__ b1, float* __restrict__ out1, int N)
{
    const int lane = threadIdx.x & 63;
    const int wid  = (blockIdx.x * 256 + threadIdx.x) >> 6;
    const int nw   = (gridDim.x * 256) >> 6;
    const int q    = lane >> 4;      // 0..3: edge slot
    const int cl8  = lane & 15;      // owns channels cl8*8 .. cl8*8+7
    const int hch  = cl8 >> 2;       // head of this channel group
    for (int n = wid; n < N; n += nw) {
        const int start = rowp[n], end = rowp[n + 1];
        const float4 ad4 = *(const float4*)(ad1 + (size_t)n * 4);
        float4 ds = {0.f, 0.f, 0.f, 0.f};
        for (int j = start + lane; j < end; j += 64) {
            int s = col[j];
            float4 a4 = *(const float4*)(as1 + (size_t)s * 4);
            ds.x += expc(leaky02(a4.x + ad4.x));
            ds.y += expc(leaky02(a4.y + ad4.y));
            ds.z += expc(leaky02(a4.z + ad4.z));
            ds.w += expc(leaky02(a4.w + ad4.w));
        }
#pragma unroll
        for (int sft = 1; sft < 64; sft <<= 1) {
            ds.x += __shfl_xor(ds.x, sft);
            ds.y += __shfl_xor(ds.y, sft);
            ds.z += __shfl_xor(ds.z, sft);
            ds.w += __shfl_xor(ds.w, sft);
        }
        const float dh  = (hch == 0) ? ds.x : (hch == 1) ? ds.y : (hch == 2) ? ds.z : ds.w;
        const float adh = (hch == 0) ? ad4.x : (hch == 1) ? ad4.y : (hch == 2) ? ad4.z : ad4.w;
        const float rdh = 1.f / (dh + 1e-16f);
        float acc[8] = {0.f,0.f,0.f,0.f,0.f,0.f,0.f,0.f};
        for (int j = start + q; j < end; j += 4) {
            int s = col[j];
            float asv = as1[(size_t)s * 4 + hch];
            float alpha = expc(leaky02(asv + adh)) * rdh;
            uint4 hv = *(const uint4*)(h1b + (size_t)s * 128 + cl8 * 8);
            acc[0] = fmaf(alpha, bflo(hv.x), acc[0]);
            acc[1] = fmaf(alpha, bfhi(hv.x), acc[1]);
            acc[2] = fmaf(alpha, bflo(hv.y), acc[2]);
            acc[3] = fmaf(alpha, bfhi(hv.y), acc[3]);
            acc[4] = fmaf(alpha, bflo(hv.z), acc[4]);
            acc[5] = fmaf(alpha, bfhi(hv.z), acc[5]);
            acc[6] = fmaf(alpha, bflo(hv.w), acc[6]);
            acc[7] = fmaf(alpha, bfhi(hv.w), acc[7]);
        }
#pragma unroll
        for (int i = 0; i < 8; ++i) {
            acc[i] += __shfl_xor(acc[i], 16);
            acc[i] += __shfl_xor(acc[i], 32);
        }
        if (q == 0) {
            float4 bv0 = *(const float4*)(b1 + cl8 * 8);
            float4 bv1 = *(const float4*)(b1 + cl8 * 8 + 4);
            float4 o0, o1;
            o0.x = eluf(acc[0] + bv0.x);
            o0.y = eluf(acc[1] + bv0.y);
            o0.z = eluf(acc[2] + bv0.z);
            o0.w = eluf(acc[3] + bv0.w);
            o1.x = eluf(acc[4] + bv1.x);
            o1.y = eluf(acc[5] + bv1.y);
            o1.z = eluf(acc[6] + bv1.z);
            o1.w = eluf(acc[7] + bv1.w);
            *(float4*)(out1 + (size_t)n * 128 + cl8 * 8)     = o0;
            *(float4*)(out1 + (size_t)n * 128 + cl8 * 8 + 4) = o1;
        }
    }
}

// ---------------- GEMM2: z2(bf16) = out1 @ w2 (+ as2/ad2) ----------------
__global__ __launch_bounds__(256, 2) void k_gemm2(
    const float* __restrict__ out1, const float* __restrict__ w2,
    const float* __restrict__ a2s, const float* __restrict__ a2d,
    unsigned short* __restrict__ z2b, float* __restrict__ as2, float* __restrict__ ad2, int N)
{
    __shared__ float xs[128 * 128];
    __shared__ float wsh[128 * 32];
    const int tid = threadIdx.x;
    const int r_base = blockIdx.x * 128;

    for (int i = tid; i < 1024; i += 256) {
        int k = i >> 3, c4 = i & 7;
        float4 v = *(const float4*)(w2 + k * 32 + c4 * 4);
        *(float4*)(wsh + k * 32 + c4 * 4) = v;
    }
    for (int i = tid; i < 4096; i += 256) {
        int r = i >> 5, k4 = i & 31;
        int rr = r_base + r; if (rr >= N) rr = N - 1;
        float4 v = *(const float4*)(out1 + (size_t)rr * 128 + k4 * 4);
        *(float4*)(xs + r * 128 + (k4 ^ (r & 7)) * 4) = v;
    }
    __syncthreads();

    const int c0 = (tid & 7) * 4;
    const int r0 = (tid >> 3) * 4;
    const int s0 = (r0 + 0) & 7, s1 = (r0 + 1) & 7, s2 = (r0 + 2) & 7, s3 = (r0 + 3) & 7;
    const float* xb0 = xs + (r0 + 0) * 128;
    const float* xb1 = xs + (r0 + 1) * 128;
    const float* xb2 = xs + (r0 + 2) * 128;
    const float* xb3 = xs + (r0 + 3) * 128;

    float4 acc0 = {0,0,0,0}, acc1 = {0,0,0,0}, acc2 = {0,0,0,0}, acc3 = {0,0,0,0};
#pragma unroll 8
    for (int k4 = 0; k4 < 32; ++k4) {
        float4 xv0 = *(const float4*)(xb0 + ((k4 ^ s0) << 2));
        float4 xv1 = *(const float4*)(xb1 + ((k4 ^ s1) << 2));
        float4 xv2 = *(const float4*)(xb2 + ((k4 ^ s2) << 2));
        float4 xv3 = *(const float4*)(xb3 + ((k4 ^ s3) << 2));
        const float* wk = wsh + k4 * 128 + c0;
        float4 w0 = *(const float4*)(wk);
        float4 w1v = *(const float4*)(wk + 32);
        float4 w2v = *(const float4*)(wk + 64);
        float4 w3 = *(const float4*)(wk + 96);
        FMA4(acc0, xv0.x, w0) FMA4(acc1, xv1.x, w0) FMA4(acc2, xv2.x, w0) FMA4(acc3, xv3.x, w0)
        FMA4(acc0, xv0.y, w1v) FMA4(acc1, xv1.y, w1v) FMA4(acc2, xv2.y, w1v) FMA4(acc3, xv3.y, w1v)
        FMA4(acc0, xv0.z, w2v) FMA4(acc1, xv1.z, w2v) FMA4(acc2, xv2.z, w2v) FMA4(acc3, xv3.z, w2v)
        FMA4(acc0, xv0.w, w3) FMA4(acc1, xv1.w, w3) FMA4(acc2, xv2.w, w3) FMA4(acc3, xv3.w, w3)
    }

    const float4 avs = *(const float4*)(a2s + c0);
    const float4 avd = *(const float4*)(a2d + c0);
    float4 accs[4] = {acc0, acc1, acc2, acc3};
#pragma unroll
    for (int i = 0; i < 4; ++i) {
        int r = r_base + r0 + i;
        float4 a = accs[i];
        float ps = a.x * avs.x + a.y * avs.y + a.z * avs.z + a.w * avs.w;
        float pd = a.x * avd.x + a.y * avd.y + a.z * avd.z + a.w * avd.w;
        ps += __shfl_xor(ps, 1); pd += __shfl_xor(pd, 1);
        ps += __shfl_xor(ps, 2); pd += __shfl_xor(pd, 2);
        ps += __shfl_xor(ps, 4); pd += __shfl_xor(pd, 4);
        if (r < N) {
            ushort4 zb;
            zb.x = f2bf(a.x); zb.y = f2bf(a.y); zb.z = f2bf(a.z); zb.w = f2bf(a.w);
            *(ushort4*)(z2b + (size_t)r * 32 + c0) = zb;
            if ((tid & 7) == 0) { as2[r] = ps; ad2[r] = pd; }
        }
    }
}

// ---------------- layer-2 aggregation + final linear (wave per dst node) ----------------
__global__ __launch_bounds__(256) void k_agg2(
    const int* __restrict__ rowp, const int* __restrict__ col,
    const float* __restrict__ as2, const float* __restrict__ ad2,
    const unsigned short* __restrict__ z2b, const float* __restrict__ b2,
    const float* __restrict__ wl, const float* __restrict__ bl,
    float* __restrict__ out, int N)
{
    const int lane = threadIdx.x & 63;
    const int wid  = (blockIdx.x * 256 + threadIdx.x) >> 6;
    const int nw   = (gridDim.x * 256) >> 6;
    const int q  = lane >> 4;
    const int cl = lane & 15;
    for (int n = wid; n < N; n += nw) {
        const int start = rowp[n], end = rowp[n + 1];
        const float adn = ad2[n];
        float d = 0.f;
        for (int j = start + lane; j < end; j += 64) {
            int s = col[j];
            d += expc(leaky02(as2[s] + adn));
        }
#pragma unroll
        for (int sft = 1; sft < 64; sft <<= 1) d += __shfl_xor(d, sft);
        const float rd = 1.f / (d + 1e-16f);
        float2 acc = {0.f, 0.f};
        for (int j = start + q; j < end; j += 4) {
            int s = col[j];
            float alpha = expc(leaky02(as2[s] + adn)) * rd;
            unsigned int zv = *(const unsigned int*)(z2b + (size_t)s * 32 + cl * 2);
            acc.x = fmaf(alpha, bflo(zv), acc.x);
            acc.y = fmaf(alpha, bfhi(zv), acc.y);
        }
        acc.x += __shfl_xor(acc.x, 16); acc.y += __shfl_xor(acc.y, 16);
        acc.x += __shfl_xor(acc.x, 32); acc.y += __shfl_xor(acc.y, 32);
        float h0 = eluf(acc.x + b2[cl * 2]);
        float h1v = eluf(acc.y + b2[cl * 2 + 1]);
        float p = h0 * wl[cl * 2] + h1v * wl[cl * 2 + 1];
#pragma unroll
        for (int sft = 1; sft < 16; sft <<= 1) p += __shfl_xor(p, sft);
        if (lane == 0) out[n] = p + bl[0];
    }
}

extern "C" void kernel_launch(void* const* d_in, const int* in_sizes, int n_in,
                              void* d_out, int out_size, void* d_ws, size_t ws_size,
                              hipStream_t stream) {
    const float* x   = (const float*)d_in[0];
    const int*   ei  = (const int*)d_in[1];
    const float* w1  = (const float*)d_in[2];
    const float* a1s = (const float*)d_in[3];
    const float* a1d = (const float*)d_in[4];
    const float* b1  = (const float*)d_in[5];
    const float* w2  = (const float*)d_in[6];
    const float* a2s = (const float*)d_in[7];
    const float* a2d = (const float*)d_in[8];
    const float* b2  = (const float*)d_in[9];
    const float* wl  = (const float*)d_in[10];
    const float* bl  = (const float*)d_in[11];
    float* out = (float*)d_out;

    const int N  = in_sizes[0] / 128;
    const int E  = in_sizes[1] / 2;
    const int Et = E + N;
    const int NB = (N + 1023) / 1024;

    float* ws   = (float*)d_ws;
    unsigned short* h1b = (unsigned short*)ws;   // N*128 bf16 = N*64 float slots
    float* out1 = ws   + (size_t)N * 64;         // N*128
    float* as1  = out1 + (size_t)N * 128;        // N*4
    float* ad1  = as1  + (size_t)N * 4;          // N*4
    unsigned short* z2b = (unsigned short*)(ad1 + (size_t)N * 4);  // N*32 bf16 = N*16 float slots
    float* as2  = ad1  + (size_t)N * 4 + (size_t)N * 16;  // N
    float* ad2  = as2  + N;                      // N
    int* counts = (int*)(ad2 + N);               // N
    int* rowp   = counts + N;                    // N+1
    int* col    = rowp + (N + 1);                // Et
    int* pos    = col + Et;                      // N
    int* bsum   = pos + N;                       // NB
    int* boff   = bsum + NB;                     // NB

    k_init1<<<(N + 255) / 256, 256, 0, stream>>>(counts, N);
    k_gemm1<<<2 * ((N + 63) / 64), 256, 0, stream>>>(x, w1, a1s, a1d, h1b, as1, ad1, N);
    k_hist<<<(E + 255) / 256, 256, 0, stream>>>(ei, counts, E);
    k_bsum<<<NB, 256, 0, stream>>>(counts, bsum, N);
    k_scansums<<<1, 1024, 0, stream>>>(bsum, boff, rowp + N, NB);
    k_scatter<<<NB, 256, 0, stream>>>(counts, boff, rowp, pos, N);
    k_fill<<<2048, 256, 0, stream>>>(ei, pos, col, E, Et, N);
    k_agg1<<<4096, 256, 0, stream>>>(rowp, col, as1, ad1, h1b, b1, out1, N);
    k_gemm2<<<(N + 127) / 128, 256, 0, stream>>>(out1, w2, a2s, a2d, z2b, as2, ad2, N);
    k_agg2<<<4096, 256, 0, stream>>>(rowp, col, as2, ad2, z2b, b2, wl, bl, out, N);
}